// Round 5
// baseline (289.941 us; speedup 1.0000x reference)
//
#include <hip/hip_runtime.h>
#include <math.h>

#define NN   1024
#define FF   32
#define HID  64
#define OUTF 32
#define ITER 8

typedef unsigned int  uint;
typedef unsigned short ushort;
typedef _Float16 halfx8  __attribute__((ext_vector_type(8)));
typedef __fp16   fp16x2  __attribute__((ext_vector_type(2)));
typedef float    floatx16 __attribute__((ext_vector_type(16)));
typedef float    floatx4  __attribute__((ext_vector_type(4)));

__device__ __forceinline__ float swish(float x) {
    // x * sigmoid(x); v_exp_f32 / v_rcp_f32, abs err ~1e-5 max — far under budget
    float e = __builtin_amdgcn_exp2f(x * -1.442695040888963f);
    return x * __builtin_amdgcn_rcpf(1.0f + e);
}

// Single fused kernel — no prep pass, no workspace, no cross-block deps.
// Each block (128 j's x 8 i's) computes its own invariants from raw inputs:
//   lA[8][64]  : A_i[h] = Emb[i] . W1[h][0:F]      (LDS, broadcast-read)
//   bv[4][8]   : B_j[h] = Emb[j] . W1[h][F:2F]     (per-lane regs, j = lane&31)
//   bhu[4]     : W2 row (lane&31) as f16 MFMA A-fragments
// Main loop: 32x32x16 f16 MFMA with SWAPPED operands (A = W2, B = h1) so
// D rows m = output o, cols n = j = lane&31 — every lane owns a contiguous
// 16-B span of its own j-row => epilogue is 4 nontemporal float4 stores.
// MFMA is interleaved per k-chunk (one ah fragment live at a time).
__global__ __launch_bounds__(256, 4) void fused_kernel(
    const float* __restrict__ Edges,
    const float* __restrict__ Coords,
    const float* __restrict__ Emb,
    const float* __restrict__ W1,
    const float* __restrict__ b1,
    const float* __restrict__ W2,
    const float* __restrict__ b2,
    float* __restrict__ out)
{
    __shared__ float lA[ITER * HID];   // A rows for i0..i0+7
    __shared__ float lb1[HID];
    __shared__ float lb2[OUTF];
    __shared__ float lci[ITER * 4];    // coords rows (x,y,z,0)

    const int t    = threadIdx.x;
    const int lane = t & 63;
    const int wave = t >> 6;
    const int j0   = blockIdx.x * 128 + wave * 32;
    const int i0   = blockIdx.y * ITER;
    const int p    = lane & 31;
    const int half = lane >> 5;
    const int jp   = j0 + p;

    // ---- prologue: A panel into LDS (all 256 threads) ----
    {
        const int r = t >> 5;          // 0..7  (i-row)
        const int h = t & 31;          // computes h and h+32
        const float* er = Emb + (size_t)(i0 + r) * FF;
        float ef[FF];
        #pragma unroll
        for (int f4 = 0; f4 < FF / 4; ++f4)
            *(float4*)(ef + f4 * 4) = ((const float4*)er)[f4];
        const float* w0 = W1 + (size_t)h * (2 * FF);
        const float* w1r = W1 + (size_t)(h + 32) * (2 * FF);
        float a0 = 0.f, a1 = 0.f;
        #pragma unroll
        for (int f4 = 0; f4 < FF / 4; ++f4) {
            const float4 q0 = ((const float4*)w0)[f4];
            const float4 q1 = ((const float4*)w1r)[f4];
            a0 = fmaf(ef[f4*4+0], q0.x, fmaf(ef[f4*4+1], q0.y,
                 fmaf(ef[f4*4+2], q0.z, fmaf(ef[f4*4+3], q0.w, a0))));
            a1 = fmaf(ef[f4*4+0], q1.x, fmaf(ef[f4*4+1], q1.y,
                 fmaf(ef[f4*4+2], q1.z, fmaf(ef[f4*4+3], q1.w, a1))));
        }
        lA[r * HID + h]      = a0;
        lA[r * HID + h + 32] = a1;
    }
    if (t < HID / 4) {                                    // t 0..15: b1
        *(float4*)&lb1[t * 4] = ((const float4*)b1)[t];
    } else if (t < HID / 4 + OUTF / 4) {                  // t 16..23: b2
        const int q = t - HID / 4;
        *(float4*)&lb2[q * 4] = ((const float4*)b2)[q];
    }
    if (t < ITER) {
        lci[t * 4 + 0] = Coords[(i0 + t) * 3 + 0];
        lci[t * 4 + 1] = Coords[(i0 + t) * 3 + 1];
        lci[t * 4 + 2] = Coords[(i0 + t) * 3 + 2];
        lci[t * 4 + 3] = 0.f;
    }

    // ---- per-lane invariants ----
    // W2 f16 fragments (MFMA A-operand): lane holds row o = p, k-slice per half
    union FragW { _Float16 h[8]; halfx8 v; } bhu[4];
    {
        const float* w2r = W2 + (size_t)p * HID;
        #pragma unroll
        for (int c = 0; c < 4; ++c) {
            const int k0 = c * 16 + half * 8;
            float wv[8];
            *(float4*)(wv + 0) = *(const float4*)(w2r + k0);
            *(float4*)(wv + 4) = *(const float4*)(w2r + k0 + 4);
            #pragma unroll
            for (int j = 0; j < 8; ++j) bhu[c].h[j] = (_Float16)wv[j];  // RNE
        }
    }
    // B_j slice: 32 dots of Emb[jp] with W1 B-half rows (fp32, L1-resident W1)
    float bv[4][8];
    {
        const float* ej = Emb + (size_t)jp * FF;
        float ef[FF];
        #pragma unroll
        for (int f4 = 0; f4 < FF / 4; ++f4)
            *(float4*)(ef + f4 * 4) = ((const float4*)ej)[f4];
        #pragma unroll
        for (int c = 0; c < 4; ++c) {
            #pragma unroll
            for (int jj = 0; jj < 8; ++jj) {
                const int h = c * 16 + half * 8 + jj;
                const float* wr = W1 + (size_t)h * (2 * FF) + FF;
                float acc = 0.f;
                #pragma unroll
                for (int f4 = 0; f4 < FF / 4; ++f4) {
                    const float4 wq = ((const float4*)wr)[f4];
                    acc = fmaf(ef[f4*4+0], wq.x, fmaf(ef[f4*4+1], wq.y,
                          fmaf(ef[f4*4+2], wq.z, fmaf(ef[f4*4+3], wq.w, acc))));
                }
                bv[c][jj] = acc;
            }
        }
    }
    const float cjx = Coords[jp * 3 + 0];
    const float cjy = Coords[jp * 3 + 1];
    const float cjz = Coords[jp * 3 + 2];

    __syncthreads();

    // Edges software pipeline
    const float* egp = Edges + (size_t)i0 * NN + jp;
    float eg = *egp;

    #pragma unroll 1
    for (int it = 0; it < ITER; ++it) {
        const int i = i0 + it;
        const float eg_cur = eg;
        if (it + 1 < ITER) eg = egp[(size_t)(it + 1) * NN];  // prefetch next row

        const float4 civ = *(const float4*)&lci[it * 4];
        const float dx = civ.x - cjx, dy = civ.y - cjy, dz = civ.z - cjz;
        const float dist = sqrtf(dx * dx + dy * dy + dz * dz);
        const float w = eg_cur * dist;

        // layer-1 + swish + pack, one k-chunk at a time, MFMA interleaved
        floatx16 acc = {0.f,0.f,0.f,0.f,0.f,0.f,0.f,0.f,
                        0.f,0.f,0.f,0.f,0.f,0.f,0.f,0.f};
        #pragma unroll
        for (int c = 0; c < 4; ++c) {
            const int ho = c * 16 + half * 8;
            float av[8], b1c[8];
            *(float4*)(av + 0)  = *(const float4*)&lA[it * HID + ho];
            *(float4*)(av + 4)  = *(const float4*)&lA[it * HID + ho + 4];
            *(float4*)(b1c + 0) = *(const float4*)&lb1[ho];
            *(float4*)(b1c + 4) = *(const float4*)&lb1[ho + 4];
            union FragH { fp16x2 h2[4]; halfx8 v; } ah;
            #pragma unroll
            for (int jj = 0; jj < 8; jj += 2) {
                const float p0 = fmaf(w, av[jj]     + bv[c][jj],     b1c[jj]);
                const float p1 = fmaf(w, av[jj + 1] + bv[c][jj + 1], b1c[jj + 1]);
                ah.h2[jj >> 1] = __builtin_amdgcn_cvt_pkrtz(swish(p0), swish(p1));
            }
            // swapped operands: D[m=o][n=j] — lane owns col j = lane&31
            acc = __builtin_amdgcn_mfma_f32_32x32x16_f16(bhu[c].v, ah.v, acc, 0, 0, 0);
        }

        // epilogue: lane's j-row, o = q*8 + half*4 .. +3 contiguous => floatx4 NT
        float* __restrict__ ob = out + ((size_t)i * NN + jp) * OUTF;
        #pragma unroll
        for (int q = 0; q < 4; ++q) {
            const float4 bb = *(const float4*)&lb2[q * 8 + half * 4];
            floatx4 v;
            v.x = swish(acc[q * 4 + 0] + bb.x);
            v.y = swish(acc[q * 4 + 1] + bb.y);
            v.z = swish(acc[q * 4 + 2] + bb.z);
            v.w = swish(acc[q * 4 + 3] + bb.w);
            __builtin_nontemporal_store(v, (floatx4*)(ob + q * 8 + half * 4));
        }
    }
}

extern "C" void kernel_launch(void* const* d_in, const int* in_sizes, int n_in,
                              void* d_out, int out_size, void* d_ws, size_t ws_size,
                              hipStream_t stream)
{
    const float* Edges  = (const float*)d_in[0];
    const float* Coords = (const float*)d_in[1];
    const float* Emb    = (const float*)d_in[2];
    const float* W1     = (const float*)d_in[3];
    const float* b1     = (const float*)d_in[4];
    const float* W2     = (const float*)d_in[5];
    const float* b2     = (const float*)d_in[6];
    float* out = (float*)d_out;
    (void)d_ws; (void)ws_size;

    hipLaunchKernelGGL(fused_kernel, dim3(NN / 128, NN / ITER), dim3(256), 0, stream,
                       Edges, Coords, Emb, W1, b1, W2, b2, out);
}

// Round 6
// 248.526 us; speedup vs baseline: 1.1666x; 1.1666x over previous
//
#include <hip/hip_runtime.h>
#include <math.h>

#define NN   1024
#define FF   32
#define HID  64
#define OUTF 32
#define ITER 4

typedef unsigned int  uint;
typedef unsigned short ushort;
typedef _Float16 halfx8  __attribute__((ext_vector_type(8)));
typedef __fp16   fp16x2  __attribute__((ext_vector_type(2)));
typedef float    floatx16 __attribute__((ext_vector_type(16)));

__device__ __forceinline__ float swish(float x) {
    // x * sigmoid(x); v_exp_f32 / v_rcp_f32, abs err ~1e-5 max — far under budget
    float e = __builtin_amdgcn_exp2f(x * -1.442695040888963f);
    return x * __builtin_amdgcn_rcpf(1.0f + e);
}

// Single fused kernel, un-swapped MFMA orientation (A = h1 rows = j-pairs,
// B = W2^T cols = outputs). D: col n = p = output o, row m = j-index — so each
// dword-store instruction covers two dense 128-B row segments (fully
// coalesced). The swapped variant (R5) scattered 16-B lane-chunks at stride
// 128 B and showed 2.3x WRITE_SIZE amplification + 170 us dispatch.
// ITER=4 doubles the grid to 2048 blocks (8/CU) to lift the 50% occupancy
// ceiling seen at ITER=8 (OccupancyPercent 34).
__global__ __launch_bounds__(256, 4) void fused_kernel(
    const float* __restrict__ Edges,
    const float* __restrict__ Coords,
    const float* __restrict__ Emb,
    const float* __restrict__ W1,
    const float* __restrict__ b1,
    const float* __restrict__ W2,
    const float* __restrict__ b2,
    float* __restrict__ out)
{
    __shared__ float lA[ITER * HID];   // A rows for i0..i0+ITER-1
    __shared__ float lb1[HID];
    __shared__ float lb2[OUTF];
    __shared__ float lci[ITER * 4];    // coords rows (x,y,z,0)

    const int t    = threadIdx.x;
    const int lane = t & 63;
    const int wave = t >> 6;
    const int j0   = blockIdx.x * 128 + wave * 32;
    const int i0   = blockIdx.y * ITER;
    const int p    = lane & 31;
    const int half = lane >> 5;
    const int jp   = j0 + p;

    // ---- prologue: A panel into LDS (ITER=4 rows x 64 h, 1 dot/thread) ----
    {
        const int r = t >> 6;          // 0..3  (i-row)
        const int h = t & 63;
        const float* er = Emb + (size_t)(i0 + r) * FF;
        const float* w0 = W1 + (size_t)h * (2 * FF);
        float a0 = 0.f;
        #pragma unroll
        for (int f4 = 0; f4 < FF / 4; ++f4) {
            const float4 e = ((const float4*)er)[f4];
            const float4 q = ((const float4*)w0)[f4];
            a0 = fmaf(e.x, q.x, fmaf(e.y, q.y, fmaf(e.z, q.z, fmaf(e.w, q.w, a0))));
        }
        lA[r * HID + h] = a0;
    }
    if (t < HID / 4) {                                    // t 0..15: b1
        *(float4*)&lb1[t * 4] = ((const float4*)b1)[t];
    } else if (t < HID / 4 + OUTF / 4) {                  // t 16..23: b2
        const int q = t - HID / 4;
        *(float4*)&lb2[q * 4] = ((const float4*)b2)[q];
    }
    if (t < ITER) {
        lci[t * 4 + 0] = Coords[(i0 + t) * 3 + 0];
        lci[t * 4 + 1] = Coords[(i0 + t) * 3 + 1];
        lci[t * 4 + 2] = Coords[(i0 + t) * 3 + 2];
        lci[t * 4 + 3] = 0.f;
    }

    // ---- per-lane invariants ----
    // W2^T f16 fragments (MFMA B-operand): n = p (output), k = c*16 + half*8 + j
    union FragW { _Float16 h[8]; halfx8 v; } bhu[4];
    {
        const float* w2r = W2 + (size_t)p * HID;
        #pragma unroll
        for (int c = 0; c < 4; ++c) {
            const int k0 = c * 16 + half * 8;
            float wv[8];
            *(float4*)(wv + 0) = *(const float4*)(w2r + k0);
            *(float4*)(wv + 4) = *(const float4*)(w2r + k0 + 4);
            #pragma unroll
            for (int j = 0; j < 8; ++j) bhu[c].h[j] = (_Float16)wv[j];  // RNE
        }
    }
    // B_j slice: 32 dots of Emb[jp] with W1 B-half rows (fp32, L1-resident W1)
    float bv[4][8];
    {
        const float* ej = Emb + (size_t)jp * FF;
        float ef[FF];
        #pragma unroll
        for (int f4 = 0; f4 < FF / 4; ++f4)
            *(float4*)(ef + f4 * 4) = ((const float4*)ej)[f4];
        #pragma unroll
        for (int c = 0; c < 4; ++c) {
            #pragma unroll
            for (int jj = 0; jj < 8; ++jj) {
                const int h = c * 16 + half * 8 + jj;
                const float* wr = W1 + (size_t)h * (2 * FF) + FF;
                float acc = 0.f;
                #pragma unroll
                for (int f4 = 0; f4 < FF / 4; ++f4) {
                    const float4 wq = ((const float4*)wr)[f4];
                    acc = fmaf(ef[f4*4+0], wq.x, fmaf(ef[f4*4+1], wq.y,
                          fmaf(ef[f4*4+2], wq.z, fmaf(ef[f4*4+3], wq.w, acc))));
                }
                bv[c][jj] = acc;
            }
        }
    }
    const float cjx = Coords[jp * 3 + 0];
    const float cjy = Coords[jp * 3 + 1];
    const float cjz = Coords[jp * 3 + 2];

    __syncthreads();

    const float b2n = lb2[p];          // output-col bias, seeds the MFMA C-in

    // Edges software pipeline
    const float* egp = Edges + (size_t)i0 * NN + jp;
    float eg = *egp;

    #pragma unroll 1
    for (int it = 0; it < ITER; ++it) {
        const int i = i0 + it;
        const float eg_cur = eg;
        if (it + 1 < ITER) eg = egp[(size_t)(it + 1) * NN];  // prefetch next row

        const float4 civ = *(const float4*)&lci[it * 4];
        const float dx = civ.x - cjx, dy = civ.y - cjy, dz = civ.z - cjz;
        const float dist = sqrtf(dx * dx + dy * dy + dz * dz);
        const float w = eg_cur * dist;

        // layer-1 + swish + pack, one k-chunk at a time, MFMA interleaved
        floatx16 acc;
        #pragma unroll
        for (int r = 0; r < 16; ++r) acc[r] = b2n;
        #pragma unroll
        for (int c = 0; c < 4; ++c) {
            const int ho = c * 16 + half * 8;
            float av[8], b1c[8];
            *(float4*)(av + 0)  = *(const float4*)&lA[it * HID + ho];
            *(float4*)(av + 4)  = *(const float4*)&lA[it * HID + ho + 4];
            *(float4*)(b1c + 0) = *(const float4*)&lb1[ho];
            *(float4*)(b1c + 4) = *(const float4*)&lb1[ho + 4];
            union FragH { fp16x2 h2[4]; halfx8 v; } ah;
            #pragma unroll
            for (int jj = 0; jj < 8; jj += 2) {
                const float p0 = fmaf(w, av[jj]     + bv[c][jj],     b1c[jj]);
                const float p1 = fmaf(w, av[jj + 1] + bv[c][jj + 1], b1c[jj + 1]);
                ah.h2[jj >> 1] = __builtin_amdgcn_cvt_pkrtz(swish(p0), swish(p1));
            }
            // un-swapped: D[m = j-idx][n = p] — store instr covers dense rows
            acc = __builtin_amdgcn_mfma_f32_32x32x16_f16(ah.v, bhu[c].v, acc, 0, 0, 0);
        }

        // epilogue: C/D layout n = p, m = (r&3) + 8*(r>>2) + 4*half
        // each NT dword-store instruction = two dense 128-B row segments
        float* __restrict__ ob = out + ((size_t)i * NN + j0) * OUTF + p;
        #pragma unroll
        for (int r = 0; r < 16; ++r) {
            const int m = (r & 3) + 8 * (r >> 2) + 4 * half;
            __builtin_nontemporal_store(swish(acc[r]), ob + m * OUTF);
        }
    }
}

extern "C" void kernel_launch(void* const* d_in, const int* in_sizes, int n_in,
                              void* d_out, int out_size, void* d_ws, size_t ws_size,
                              hipStream_t stream)
{
    const float* Edges  = (const float*)d_in[0];
    const float* Coords = (const float*)d_in[1];
    const float* Emb    = (const float*)d_in[2];
    const float* W1     = (const float*)d_in[3];
    const float* b1     = (const float*)d_in[4];
    const float* W2     = (const float*)d_in[5];
    const float* b2     = (const float*)d_in[6];
    float* out = (float*)d_out;
    (void)d_ws; (void)ws_size;

    hipLaunchKernelGGL(fused_kernel, dim3(NN / 128, NN / ITER), dim3(256), 0, stream,
                       Edges, Coords, Emb, W1, b1, W2, b2, out);
}

// Round 10
// 243.550 us; speedup vs baseline: 1.1905x; 1.0204x over previous
//
#include <hip/hip_runtime.h>
#include <math.h>

#define NN   1024
#define FF   32
#define HID  64
#define OUTF 32
#define ITER 8

typedef unsigned int  uint;
typedef unsigned short ushort;
typedef _Float16 halfx8  __attribute__((ext_vector_type(8)));
typedef __fp16   fp16x2  __attribute__((ext_vector_type(2)));
typedef float    floatx16 __attribute__((ext_vector_type(16)));

// ws layout (float offsets)
#define WS_A    0                      // N*HID
#define WS_B    (WS_A + NN*HID)        // 65536
#define WS_C4   (WS_B + NN*HID)        // 131072  (N x 4: x,y,z,0)
#define WS_B1   (WS_C4 + NN*4)         // 135168
#define WS_B2   (WS_B1 + HID)          // 135232 (pad to 64)
#define WS_W2H  (WS_B2 + 64)           // 135296  ushort[4*64*8] = 1024 floats

__device__ __forceinline__ float swish(float x) {
    // x * sigmoid(x); v_exp_f32 / v_rcp_f32, abs err ~1e-5 max — far under budget
    float e = __builtin_amdgcn_exp2f(x * -1.442695040888963f);
    return x * __builtin_amdgcn_rcpf(1.0f + e);
}

__global__ void prep_kernel(
    const float* __restrict__ Coords,
    const float* __restrict__ Emb,
    const float* __restrict__ W1,
    const float* __restrict__ b1,
    const float* __restrict__ W2,
    const float* __restrict__ b2,
    float* __restrict__ ws)
{
    const int b = blockIdx.x;
    const int t = threadIdx.x;
    if (b < NN) {
        // A[b][t] = Emb[b] . W1[t][0:F];  B[b][t] = Emb[b] . W1[t][F:2F]
        const float4* w1v = (const float4*)(W1 + t * (2 * FF));
        const float4* ev  = (const float4*)(Emb + b * FF);
        float accA = 0.f, accB = 0.f;
        #pragma unroll
        for (int f4 = 0; f4 < FF / 4; ++f4) {
            const float4 e  = ev[f4];
            const float4 a  = w1v[f4];
            const float4 bq = w1v[FF / 4 + f4];
            accA = fmaf(e.x, a.x,  fmaf(e.y, a.y,  fmaf(e.z, a.z,  fmaf(e.w, a.w,  accA))));
            accB = fmaf(e.x, bq.x, fmaf(e.y, bq.y, fmaf(e.z, bq.z, fmaf(e.w, bq.w, accB))));
        }
        ws[WS_A + b * HID + t] = accA;
        ws[WS_B + b * HID + t] = accB;
    } else {
        if (t < HID)  ws[WS_B1 + t] = b1[t];
        if (t < OUTF) ws[WS_B2 + t] = b2[t];
        #pragma unroll 1
        for (int n = t; n < NN; n += 64) {
            ws[WS_C4 + n * 4 + 0] = Coords[n * 3 + 0];
            ws[WS_C4 + n * 4 + 1] = Coords[n * 3 + 1];
            ws[WS_C4 + n * 4 + 2] = Coords[n * 3 + 2];
            ws[WS_C4 + n * 4 + 3] = 0.f;
        }
        // W2^T fragments in MFMA B-layout (32x32x16): n = t&31, k = (t>>5)*8 + j
        // f16 RNE (2^-11 rel err)
        ushort* w2h = (ushort*)(ws + WS_W2H);
        const int n  = t & 31;
        const int kh = (t >> 5) * 8;
        #pragma unroll
        for (int c = 0; c < 4; ++c) {
            #pragma unroll
            for (int j = 0; j < 8; ++j) {
                const int k = c * 16 + kh + j;
                union { _Float16 h; ushort u; } cv;
                cv.h = (_Float16)W2[n * HID + k];
                w2h[(c * 64 + t) * 8 + j] = cv.u;
            }
        }
    }
}

// Two-kernel structure (R2 baseline, best measured) + DUAL-I ILP.
// R6 counters showed the main loop is a pure latency chain (all blocks
// co-resident, VALUBusy 31%, MfmaUtil 1.3%, HBM 17% — nothing saturated).
// Fix: process two i's per loop step with independent acc chains; the two
// swish/pack/MFMA streams interleave, doubling issue per chain traversal.
// Shared invariants (bv, W2 frags, b1, cj) amortize across both chains.
__global__ __launch_bounds__(256, 4) void main_kernel(
    const float* __restrict__ Edges,
    const float* __restrict__ ws,
    float* __restrict__ out)
{
    __shared__ float lds[ITER * HID + HID + ITER * 4]; // A rows | b1 | ci rows

    const int t    = threadIdx.x;
    const int lane = t & 63;
    const int wave = t >> 6;
    const int j0   = blockIdx.x * 128 + wave * 32;
    const int i0   = blockIdx.y * ITER;
    const int p    = lane & 31;
    const int half = lane >> 5;
    const int jp   = j0 + p;

    // ---- stage LDS: A[i0..i0+7][64], b1[64], C4[i0..i0+7] ----
    {
        const float* srcA = ws + WS_A + (size_t)i0 * HID;   // 512 contiguous floats
        if (t < 128) {
            *(float4*)&lds[t * 4] = *(const float4*)(srcA + t * 4);
        } else if (t < 144) {
            *(float4*)&lds[ITER * HID + (t - 128) * 4] =
                *(const float4*)(ws + WS_B1 + (t - 128) * 4);
        } else if (t < 152) {
            *(float4*)&lds[ITER * HID + HID + (t - 144) * 4] =
                *(const float4*)(ws + WS_C4 + (size_t)(i0 + (t - 144)) * 4);
        }
    }

    // ---- loop-invariant state (VGPRs) ----
    const ushort* w2hp = (const ushort*)(ws + WS_W2H);
    halfx8 bh[4];
    #pragma unroll
    for (int c = 0; c < 4; ++c)
        bh[c] = *(const halfx8*)(w2hp + (c * 64 + lane) * 8);

    const float* __restrict__ Bj = ws + WS_B + (size_t)jp * HID;
    float bv[4][8];
    #pragma unroll
    for (int c = 0; c < 4; ++c) {
        const int h0 = c * 16 + half * 8;
        *(float4*)(&bv[c][0]) = *(const float4*)(Bj + h0);
        *(float4*)(&bv[c][4]) = *(const float4*)(Bj + h0 + 4);
    }
    const float4 cj  = *(const float4*)(ws + WS_C4 + (size_t)jp * 4);
    const float  b2n = ws[WS_B2 + p];

    __syncthreads();

    // Edges software pipeline: two rows in flight
    const float* egp = Edges + (size_t)i0 * NN + jp;
    float eg0 = egp[0];
    float eg1 = egp[NN];

    #pragma unroll 1
    for (int it = 0; it < ITER; it += 2) {
        const float e0 = eg0, e1 = eg1;
        if (it + 2 < ITER) {                 // prefetch next pair
            eg0 = egp[(size_t)(it + 2) * NN];
            eg1 = egp[(size_t)(it + 3) * NN];
        }

        const float4 ci0 = *(const float4*)&lds[ITER * HID + HID + it * 4];
        const float4 ci1 = *(const float4*)&lds[ITER * HID + HID + (it + 1) * 4];
        const float dx0 = ci0.x - cj.x, dy0 = ci0.y - cj.y, dz0 = ci0.z - cj.z;
        const float dx1 = ci1.x - cj.x, dy1 = ci1.y - cj.y, dz1 = ci1.z - cj.z;
        const float w0 = e0 * sqrtf(dx0 * dx0 + dy0 * dy0 + dz0 * dz0);
        const float w1 = e1 * sqrtf(dx1 * dx1 + dy1 * dy1 + dz1 * dz1);

        // layer-1 + swish + pack for BOTH i's; two independent MFMA chains
        floatx16 acc0, acc1;
        #pragma unroll
        for (int r = 0; r < 16; ++r) { acc0[r] = b2n; acc1[r] = b2n; }
        #pragma unroll
        for (int c = 0; c < 4; ++c) {
            const int ho = c * 16 + half * 8;
            float av0[8], av1[8], b1c[8];
            *(float4*)(av0 + 0) = *(const float4*)&lds[it * HID + ho];
            *(float4*)(av0 + 4) = *(const float4*)&lds[it * HID + ho + 4];
            *(float4*)(av1 + 0) = *(const float4*)&lds[(it + 1) * HID + ho];
            *(float4*)(av1 + 4) = *(const float4*)&lds[(it + 1) * HID + ho + 4];
            *(float4*)(b1c + 0) = *(const float4*)&lds[ITER * HID + ho];
            *(float4*)(b1c + 4) = *(const float4*)&lds[ITER * HID + ho + 4];
            union FragH { fp16x2 h2[4]; halfx8 v; } ah0, ah1;
            #pragma unroll
            for (int jj = 0; jj < 8; jj += 2) {
                const float q0 = fmaf(w0, av0[jj]     + bv[c][jj],     b1c[jj]);
                const float q1 = fmaf(w0, av0[jj + 1] + bv[c][jj + 1], b1c[jj + 1]);
                const float r0 = fmaf(w1, av1[jj]     + bv[c][jj],     b1c[jj]);
                const float r1 = fmaf(w1, av1[jj + 1] + bv[c][jj + 1], b1c[jj + 1]);
                ah0.h2[jj >> 1] = __builtin_amdgcn_cvt_pkrtz(swish(q0), swish(q1));
                ah1.h2[jj >> 1] = __builtin_amdgcn_cvt_pkrtz(swish(r0), swish(r1));
            }
            acc0 = __builtin_amdgcn_mfma_f32_32x32x16_f16(ah0.v, bh[c], acc0, 0, 0, 0);
            acc1 = __builtin_amdgcn_mfma_f32_32x32x16_f16(ah1.v, bh[c], acc1, 0, 0, 0);
        }

        // epilogue: C/D layout n = p (output), m = (r&3) + 8*(r>>2) + 4*half (j)
        // two store bursts (one per i-row) — each NT dword-store instruction
        // covers two dense 128-B row segments
        float* __restrict__ ob0 = out + ((size_t)(i0 + it)     * NN + j0) * OUTF + p;
        #pragma unroll
        for (int r = 0; r < 16; ++r) {
            const int m = (r & 3) + 8 * (r >> 2) + 4 * half;
            __builtin_nontemporal_store(swish(acc0[r]), ob0 + m * OUTF);
        }
        float* __restrict__ ob1 = out + ((size_t)(i0 + it + 1) * NN + j0) * OUTF + p;
        #pragma unroll
        for (int r = 0; r < 16; ++r) {
            const int m = (r & 3) + 8 * (r >> 2) + 4 * half;
            __builtin_nontemporal_store(swish(acc1[r]), ob1 + m * OUTF);
        }
    }
}

extern "C" void kernel_launch(void* const* d_in, const int* in_sizes, int n_in,
                              void* d_out, int out_size, void* d_ws, size_t ws_size,
                              hipStream_t stream)
{
    const float* Edges  = (const float*)d_in[0];
    const float* Coords = (const float*)d_in[1];
    const float* Emb    = (const float*)d_in[2];
    const float* W1     = (const float*)d_in[3];
    const float* b1     = (const float*)d_in[4];
    const float* W2     = (const float*)d_in[5];
    const float* b2     = (const float*)d_in[6];
    float* ws  = (float*)d_ws;
    float* out = (float*)d_out;

    hipLaunchKernelGGL(prep_kernel, dim3(NN + 1), dim3(64), 0, stream,
                       Coords, Emb, W1, b1, W2, b2, ws);
    hipLaunchKernelGGL(main_kernel, dim3(NN / 128, NN / ITER), dim3(256), 0, stream,
                       Edges, ws, out);
}

// Round 11
// 187.479 us; speedup vs baseline: 1.5465x; 1.2991x over previous
//
#include <hip/hip_runtime.h>
#include <math.h>

#define NN   1024
#define FF   32
#define HID  64
#define OUTF 32
#define ITER 4

typedef unsigned int  uint;
typedef unsigned short ushort;
typedef _Float16 halfx8  __attribute__((ext_vector_type(8)));
typedef __fp16   fp16x2  __attribute__((ext_vector_type(2)));
typedef float    floatx16 __attribute__((ext_vector_type(16)));

// ws layout (float offsets)
#define WS_A    0                      // N*HID
#define WS_B    (WS_A + NN*HID)        // 65536
#define WS_C4   (WS_B + NN*HID)        // 131072  (N x 4: x,y,z,0)
#define WS_B1   (WS_C4 + NN*4)         // 135168
#define WS_B2   (WS_B1 + HID)          // 135232 (pad to 64)
#define WS_W2H  (WS_B2 + 64)           // 135296  ushort[4*64*8] = 1024 floats

__device__ __forceinline__ float swish(float x) {
    // x * sigmoid(x); v_exp_f32 / v_rcp_f32, abs err ~1e-5 max — far under budget
    float e = __builtin_amdgcn_exp2f(x * -1.442695040888963f);
    return x * __builtin_amdgcn_rcpf(1.0f + e);
}

__global__ void prep_kernel(
    const float* __restrict__ Coords,
    const float* __restrict__ Emb,
    const float* __restrict__ W1,
    const float* __restrict__ b1,
    const float* __restrict__ W2,
    const float* __restrict__ b2,
    float* __restrict__ ws)
{
    const int b = blockIdx.x;
    const int t = threadIdx.x;
    if (b < NN) {
        // A[b][t] = Emb[b] . W1[t][0:F];  B[b][t] = Emb[b] . W1[t][F:2F]
        const float4* w1v = (const float4*)(W1 + t * (2 * FF));
        const float4* ev  = (const float4*)(Emb + b * FF);
        float accA = 0.f, accB = 0.f;
        #pragma unroll
        for (int f4 = 0; f4 < FF / 4; ++f4) {
            const float4 e  = ev[f4];
            const float4 a  = w1v[f4];
            const float4 bq = w1v[FF / 4 + f4];
            accA = fmaf(e.x, a.x,  fmaf(e.y, a.y,  fmaf(e.z, a.z,  fmaf(e.w, a.w,  accA))));
            accB = fmaf(e.x, bq.x, fmaf(e.y, bq.y, fmaf(e.z, bq.z, fmaf(e.w, bq.w, accB))));
        }
        ws[WS_A + b * HID + t] = accA;
        ws[WS_B + b * HID + t] = accB;
    } else {
        if (t < HID)  ws[WS_B1 + t] = b1[t];
        if (t < OUTF) ws[WS_B2 + t] = b2[t];
        #pragma unroll 1
        for (int n = t; n < NN; n += 64) {
            ws[WS_C4 + n * 4 + 0] = Coords[n * 3 + 0];
            ws[WS_C4 + n * 4 + 1] = Coords[n * 3 + 1];
            ws[WS_C4 + n * 4 + 2] = Coords[n * 3 + 2];
            ws[WS_C4 + n * 4 + 3] = 0.f;
        }
        // W2^T fragments in MFMA B-layout (32x32x16): n = t&31, k = (t>>5)*8 + j
        // f16 RNE (2^-11 rel err)
        ushort* w2h = (ushort*)(ws + WS_W2H);
        const int n  = t & 31;
        const int kh = (t >> 5) * 8;
        #pragma unroll
        for (int c = 0; c < 4; ++c) {
            #pragma unroll
            for (int j = 0; j < 8; ++j) {
                const int k = c * 16 + kh + j;
                union { _Float16 h; ushort u; } cv;
                cv.h = (_Float16)W2[n * HID + k];
                w2h[(c * 64 + t) * 8 + j] = cv.u;
            }
        }
    }
}

// R2 structure (single-i, best measured) with ITER=4 for 2x TLP.
// R10 post-mortem: dual-i ILP spilled (FETCH 159 MB of scratch traffic,
// main 117 us). Issue-cycle floor for this loop is ~25 us but measured ~80
// at 16 waves/CU — latency-stall-bound. ITER=4 doubles the grid to 2048
// blocks = 8 blocks/CU = up to 32 waves/CU; single-i register footprint
// stays well under the 128-VGPR cap so residency is grid-limited only.
__global__ __launch_bounds__(256, 4) void main_kernel(
    const float* __restrict__ Edges,
    const float* __restrict__ ws,
    float* __restrict__ out)
{
    __shared__ float lds[ITER * HID + HID + ITER * 4]; // A rows | b1 | ci rows

    const int t    = threadIdx.x;
    const int lane = t & 63;
    const int wave = t >> 6;
    const int j0   = blockIdx.x * 128 + wave * 32;
    const int i0   = blockIdx.y * ITER;
    const int p    = lane & 31;
    const int half = lane >> 5;
    const int jp   = j0 + p;

    // ---- stage LDS: A[i0..i0+3][64] (64 float4), b1 (16 float4), C4 (4 float4)
    {
        const float* srcA = ws + WS_A + (size_t)i0 * HID;   // 256 contiguous floats
        if (t < 64) {
            *(float4*)&lds[t * 4] = *(const float4*)(srcA + t * 4);
        } else if (t < 80) {
            *(float4*)&lds[ITER * HID + (t - 64) * 4] =
                *(const float4*)(ws + WS_B1 + (t - 64) * 4);
        } else if (t < 84) {
            *(float4*)&lds[ITER * HID + HID + (t - 80) * 4] =
                *(const float4*)(ws + WS_C4 + (size_t)(i0 + (t - 80)) * 4);
        }
    }

    // ---- loop-invariant state (VGPRs) ----
    const ushort* w2hp = (const ushort*)(ws + WS_W2H);
    halfx8 bh[4];
    #pragma unroll
    for (int c = 0; c < 4; ++c)
        bh[c] = *(const halfx8*)(w2hp + (c * 64 + lane) * 8);

    const float* __restrict__ Bj = ws + WS_B + (size_t)jp * HID;
    float bv[4][8];
    #pragma unroll
    for (int c = 0; c < 4; ++c) {
        const int h0 = c * 16 + half * 8;
        *(float4*)(&bv[c][0]) = *(const float4*)(Bj + h0);
        *(float4*)(&bv[c][4]) = *(const float4*)(Bj + h0 + 4);
    }
    const float4 cj  = *(const float4*)(ws + WS_C4 + (size_t)jp * 4);
    const float  b2n = ws[WS_B2 + p];

    __syncthreads();

    // Edges software pipeline
    const float* egp = Edges + (size_t)i0 * NN + jp;
    float eg = *egp;

    #pragma unroll 1
    for (int it = 0; it < ITER; ++it) {
        const int i = i0 + it;
        const float eg_cur = eg;
        if (it + 1 < ITER) eg = egp[(size_t)(it + 1) * NN];  // prefetch next row

        // ci via LDS broadcast (all lanes same addr = free)
        const float4 civ = *(const float4*)&lds[ITER * HID + HID + it * 4];
        const float dx = civ.x - cj.x, dy = civ.y - cj.y, dz = civ.z - cj.z;
        const float dist = sqrtf(dx * dx + dy * dy + dz * dz);
        const float w = eg_cur * dist;

        // layer-1 + swish; pack straight to f16 (RTZ)
        floatx16 acc;
        #pragma unroll
        for (int r = 0; r < 16; ++r) acc[r] = b2n;
        #pragma unroll
        for (int c = 0; c < 4; ++c) {
            const int ho = c * 16 + half * 8;
            float av[8], b1c[8];
            *(float4*)(av + 0)  = *(const float4*)&lds[it * HID + ho];
            *(float4*)(av + 4)  = *(const float4*)&lds[it * HID + ho + 4];
            *(float4*)(b1c + 0) = *(const float4*)&lds[ITER * HID + ho];
            *(float4*)(b1c + 4) = *(const float4*)&lds[ITER * HID + ho + 4];
            union FragH { fp16x2 h2[4]; halfx8 v; } ah;
            #pragma unroll
            for (int jj = 0; jj < 8; jj += 2) {
                const float p0 = fmaf(w, av[jj]     + bv[c][jj],     b1c[jj]);
                const float p1 = fmaf(w, av[jj + 1] + bv[c][jj + 1], b1c[jj + 1]);
                ah.h2[jj >> 1] = __builtin_amdgcn_cvt_pkrtz(swish(p0), swish(p1));
            }
            acc = __builtin_amdgcn_mfma_f32_32x32x16_f16(ah.v, bh[c], acc, 0, 0, 0);
        }

        // epilogue: C/D layout n = p (output), m = (r&3) + 8*(r>>2) + 4*half (j)
        // each NT dword-store instruction covers two dense 128-B row segments
        float* __restrict__ ob = out + ((size_t)i * NN + j0) * OUTF + p;
        #pragma unroll
        for (int r = 0; r < 16; ++r) {
            const int m = (r & 3) + 8 * (r >> 2) + 4 * half;
            __builtin_nontemporal_store(swish(acc[r]), ob + m * OUTF);
        }
    }
}

extern "C" void kernel_launch(void* const* d_in, const int* in_sizes, int n_in,
                              void* d_out, int out_size, void* d_ws, size_t ws_size,
                              hipStream_t stream)
{
    const float* Edges  = (const float*)d_in[0];
    const float* Coords = (const float*)d_in[1];
    const float* Emb    = (const float*)d_in[2];
    const float* W1     = (const float*)d_in[3];
    const float* b1     = (const float*)d_in[4];
    const float* W2     = (const float*)d_in[5];
    const float* b2     = (const float*)d_in[6];
    float* ws  = (float*)d_ws;
    float* out = (float*)d_out;

    hipLaunchKernelGGL(prep_kernel, dim3(NN + 1), dim3(64), 0, stream,
                       Coords, Emb, W1, b1, W2, b2, ws);
    hipLaunchKernelGGL(main_kernel, dim3(NN / 128, NN / ITER), dim3(256), 0, stream,
                       Edges, ws, out);
}